// Round 1
// baseline (8258.883 us; speedup 1.0000x reference)
//
#include <hip/hip_runtime.h>

#define TS   576
#define HID  128
#define GT   512     // 4*HID
#define K0   144     // 15 (x, emb-folded) + 128 (h0) + 1 pad
#define K1   256     // 128 (out0) + 128 (h1)
#define BB   8       // batch rows per block
#define NT   1024    // threads per block

// static device scratch for prepped weights (avoids d_ws size assumptions)
#define WT0_OFF   0
#define B0_OFF    (K0*GT)            // 73728
#define WT1_OFF   (B0_OFF + GT)      // 74240
#define B1_OFF    (WT1_OFF + K1*GT)  // 205312
#define WS_FLOATS (B1_OFF + GT)      // 205824
__device__ float g_ws[WS_FLOATS];

__global__ void prep_kernel(const float* __restrict__ W_emb, const float* __restrict__ b_emb,
                            const float* __restrict__ W_ih0, const float* __restrict__ W_hh0,
                            const float* __restrict__ b_ih0, const float* __restrict__ b_hh0,
                            const float* __restrict__ W_ih1, const float* __restrict__ W_hh1,
                            const float* __restrict__ b_ih1, const float* __restrict__ b_hh1)
{
    const int j = blockIdx.x * blockDim.x + threadIdx.x;
    if (j >= GT) return;
    float* Wt0 = g_ws + WT0_OFF;
    float* b0  = g_ws + B0_OFF;
    float* Wt1 = g_ws + WT1_OFF;
    float* b1  = g_ws + B1_OFF;

    // fold embedding: Wcomb[j][i] = sum_c W_ih0[j][c] * W_emb[c][i]  (k-major store)
    for (int i = 0; i < 15; ++i) {
        float s = 0.f;
        for (int c = 0; c < 32; ++c) s = fmaf(W_ih0[j*32 + c], W_emb[c*15 + i], s);
        Wt0[i*GT + j] = s;
    }
    for (int k = 0; k < HID; ++k) Wt0[(15 + k)*GT + j] = W_hh0[j*HID + k];
    Wt0[143*GT + j] = 0.f;  // pad row
    float bb = b_ih0[j] + b_hh0[j];
    for (int c = 0; c < 32; ++c) bb = fmaf(W_ih0[j*32 + c], b_emb[c], bb);
    b0[j] = bb;

    for (int k = 0; k < HID; ++k) Wt1[k*GT + j]         = W_ih1[j*HID + k];
    for (int k = 0; k < HID; ++k) Wt1[(HID + k)*GT + j] = W_hh1[j*HID + k];
    b1[j] = b_ih1[j] + b_hh1[j];
}

__device__ __forceinline__ float sigm(float v) { return 1.f / (1.f + __expf(-v)); }

#define FMAQ(A, S) \
    A[0] = fmaf(S.x, w0.x, A[0]); A[1] = fmaf(S.x, w0.y, A[1]); A[2] = fmaf(S.x, w0.z, A[2]); A[3] = fmaf(S.x, w0.w, A[3]); \
    A[0] = fmaf(S.y, w1.x, A[0]); A[1] = fmaf(S.y, w1.y, A[1]); A[2] = fmaf(S.y, w1.z, A[2]); A[3] = fmaf(S.y, w1.w, A[3]); \
    A[0] = fmaf(S.z, w2.x, A[0]); A[1] = fmaf(S.z, w2.y, A[1]); A[2] = fmaf(S.z, w2.z, A[2]); A[3] = fmaf(S.z, w2.w, A[3]); \
    A[0] = fmaf(S.w, w3.x, A[0]); A[1] = fmaf(S.w, w3.y, A[1]); A[2] = fmaf(S.w, w3.z, A[2]); A[3] = fmaf(S.w, w3.w, A[3]);

// one k-split GEMM slice: 4 cols (q4..q4+3) x 4 rows, NCH chunks of 4 k
template<int NCH>
__device__ __forceinline__ void gemm_phase(const float* __restrict__ wp,
                                           const float* sp0, const float* sp1,
                                           const float* sp2, const float* sp3,
                                           float4 binit, float* pp, int q4)
{
    float a[4][4];
    a[0][0]=a[1][0]=a[2][0]=a[3][0]=binit.x;
    a[0][1]=a[1][1]=a[2][1]=a[3][1]=binit.y;
    a[0][2]=a[1][2]=a[2][2]=a[3][2]=binit.z;
    a[0][3]=a[1][3]=a[2][3]=a[3][3]=binit.w;
    #pragma unroll 2
    for (int ch = 0; ch < NCH; ++ch) {
        float4 w0 = *(const float4*)(wp);
        float4 w1 = *(const float4*)(wp +     GT);
        float4 w2 = *(const float4*)(wp + 2 * GT);
        float4 w3 = *(const float4*)(wp + 3 * GT);
        wp += 4 * GT;
        float4 s0 = *(const float4*)(sp0); sp0 += 4;
        float4 s1 = *(const float4*)(sp1); sp1 += 4;
        float4 s2 = *(const float4*)(sp2); sp2 += 4;
        float4 s3 = *(const float4*)(sp3); sp3 += 4;
        FMAQ(a[0], s0); FMAQ(a[1], s1); FMAQ(a[2], s2); FMAQ(a[3], s3);
    }
    *(float4*)(pp + 0*GT + q4) = make_float4(a[0][0], a[0][1], a[0][2], a[0][3]);
    *(float4*)(pp + 1*GT + q4) = make_float4(a[1][0], a[1][1], a[1][2], a[1][3]);
    *(float4*)(pp + 2*GT + q4) = make_float4(a[2][0], a[2][1], a[2][2], a[2][3]);
    *(float4*)(pp + 3*GT + q4) = make_float4(a[3][0], a[3][1], a[3][2], a[3][3]);
}

__global__ __launch_bounds__(NT, 4) void lstm_main(
    const float* __restrict__ x,
    const float* __restrict__ W_fc1, const float* __restrict__ b_fc1,
    const float* __restrict__ W_fc2, const float* __restrict__ b_fc2,
    float* __restrict__ out)
{
    __shared__ float src0[BB][K0];       // [15 x-cols | 128 h0 | pad]
    __shared__ float src1[BB][K1];       // [128 out0 | 128 h1]
    __shared__ float part[4][BB][GT];    // k-split partial sums (64 KB)

    const float* Wt0 = g_ws + WT0_OFF;
    const float* bs0 = g_ws + B0_OFF;
    const float* Wt1 = g_ws + WT1_OFF;
    const float* bs1 = g_ws + B1_OFF;

    const int tid  = threadIdx.x;
    const int q4   = (tid & 127) << 2;        // col quad base
    const int rh4  = ((tid >> 7) & 1) << 2;   // GEMM row base: 0 or 4
    const int ks   = tid >> 8;                // k-split 0..3
    const int um   = tid & 127;               // update: unit
    const int ur   = tid >> 7;                // update: row 0..7
    const int row0 = blockIdx.x * BB;

    for (int i = tid; i < BB*K0; i += NT) (&src0[0][0])[i] = 0.f;
    for (int i = tid; i < BB*K1; i += NT) (&src1[0][0])[i] = 0.f;

    const float4 bq0 = *(const float4*)(bs0 + q4);
    const float4 bq1 = *(const float4*)(bs1 + q4);
    const float4 zz  = make_float4(0.f, 0.f, 0.f, 0.f);
    const float4 i0  = (ks == 0) ? bq0 : zz;   // bias folded into ks==0 partial
    const float4 i1  = (ks == 0) ? bq1 : zz;
    float c0 = 0.f, c1 = 0.f;

    // x loader role (threads 0..119 load 8 rows x 15 features)
    const int lr = tid / 15, li = tid - lr * 15;
    const float* xp = x + (size_t)(row0 + (tid < 120 ? lr : 0)) * (TS * 15) + (tid < 120 ? li : 0);

    __syncthreads();
    if (tid < 120) src0[lr][li] = xp[0];
    __syncthreads();

    const int k0b = ks * 36;   // L0 k-range [k0b, k0b+36)
    const int k1b = ks * 64;   // L1 k-range [k1b, k1b+64)
    const float* w0base = Wt0 + (size_t)k0b * GT + q4;
    const float* w1base = Wt1 + (size_t)k1b * GT + q4;
    float* pbase = &part[ks][rh4][0];

    for (int t = 0; t < TS; ++t) {
        // ---- L0 GEMM: gates += [x|h0] @ Wt0 ----
        gemm_phase<9>(w0base,
                      &src0[rh4 + 0][k0b], &src0[rh4 + 1][k0b],
                      &src0[rh4 + 2][k0b], &src0[rh4 + 3][k0b],
                      i0, pbase, q4);
        __syncthreads();
        // ---- L0 cell update ----
        {
            float gi = part[0][ur][um]        + part[1][ur][um]        + part[2][ur][um]        + part[3][ur][um];
            float gf = part[0][ur][128 + um]  + part[1][ur][128 + um]  + part[2][ur][128 + um]  + part[3][ur][128 + um];
            float gg = part[0][ur][256 + um]  + part[1][ur][256 + um]  + part[2][ur][256 + um]  + part[3][ur][256 + um];
            float go = part[0][ur][384 + um]  + part[1][ur][384 + um]  + part[2][ur][384 + um]  + part[3][ur][384 + um];
            float iv = sigm(gi), fv = sigm(gf), ov = sigm(go);
            float gv = tanhf(gg);
            c0 = fmaf(fv, c0, iv * gv);
            float hv = ov * tanhf(c0);
            src0[ur][15 + um] = hv;   // h0 for next step's L0 GEMM
            src1[ur][um]      = hv;   // out0[t] feeding L1
        }
        __syncthreads();
        // ---- L1 GEMM (+ prefetch next x slab into src0[:, 0:15]) ----
        if (t + 1 < TS && tid < 120) src0[lr][li] = xp[(size_t)(t + 1) * 15];
        gemm_phase<16>(w1base,
                       &src1[rh4 + 0][k1b], &src1[rh4 + 1][k1b],
                       &src1[rh4 + 2][k1b], &src1[rh4 + 3][k1b],
                       i1, pbase, q4);
        __syncthreads();
        // ---- L1 cell update ----
        {
            float gi = part[0][ur][um]        + part[1][ur][um]        + part[2][ur][um]        + part[3][ur][um];
            float gf = part[0][ur][128 + um]  + part[1][ur][128 + um]  + part[2][ur][128 + um]  + part[3][ur][128 + um];
            float gg = part[0][ur][256 + um]  + part[1][ur][256 + um]  + part[2][ur][256 + um]  + part[3][ur][256 + um];
            float go = part[0][ur][384 + um]  + part[1][ur][384 + um]  + part[2][ur][384 + um]  + part[3][ur][384 + um];
            float iv = sigm(gi), fv = sigm(gf), ov = sigm(go);
            float gv = tanhf(gg);
            c1 = fmaf(fv, c1, iv * gv);
            float hv = ov * tanhf(c1);
            src1[ur][128 + um] = hv;  // h1
        }
        __syncthreads();
    }

    // ---- FC head: relu(h1 @ W_fc1^T + b_fc1) @ W_fc2^T + b_fc2 ----
    if (tid < BB * 64) {
        const int rr = tid >> 6, u = tid & 63;
        float acc = b_fc1[u];
        #pragma unroll 8
        for (int k = 0; k < HID; ++k) acc = fmaf(src1[rr][HID + k], W_fc1[u*HID + k], acc);
        part[0][rr][u] = fmaxf(acc, 0.f);
    }
    __syncthreads();
    if (tid < BB) {
        float acc = b_fc2[0];
        #pragma unroll 8
        for (int u = 0; u < 64; ++u) acc = fmaf(part[0][tid][u], W_fc2[u], acc);
        out[row0 + tid] = acc;
    }
}

extern "C" void kernel_launch(void* const* d_in, const int* in_sizes, int n_in,
                              void* d_out, int out_size, void* d_ws, size_t ws_size,
                              hipStream_t stream)
{
    const float* x     = (const float*)d_in[0];
    const float* W_emb = (const float*)d_in[1];
    const float* b_emb = (const float*)d_in[2];
    const float* W_ih0 = (const float*)d_in[3];
    const float* W_hh0 = (const float*)d_in[4];
    const float* b_ih0 = (const float*)d_in[5];
    const float* b_hh0 = (const float*)d_in[6];
    const float* W_ih1 = (const float*)d_in[7];
    const float* W_hh1 = (const float*)d_in[8];
    const float* b_ih1 = (const float*)d_in[9];
    const float* b_hh1 = (const float*)d_in[10];
    const float* W_fc1 = (const float*)d_in[11];
    const float* b_fc1 = (const float*)d_in[12];
    const float* W_fc2 = (const float*)d_in[13];
    const float* b_fc2 = (const float*)d_in[14];
    float* out = (float*)d_out;

    prep_kernel<<<2, 256, 0, stream>>>(W_emb, b_emb, W_ih0, W_hh0, b_ih0, b_hh0,
                                       W_ih1, W_hh1, b_ih1, b_hh1);
    lstm_main<<<2048 / BB, NT, 0, stream>>>(x, W_fc1, b_fc1, W_fc2, b_fc2, out);
}